// Round 20
// baseline (337.952 us; speedup 1.0000x reference)
//
#include <hip/hip_runtime.h>
#include <hip/hip_bf16.h>
#include <stdint.h>

// ResRnn via first-order expansion in eps (method err ~1e-3 << 2.62):
//   tables: pi^t / pi^-t via composition doubling (+ u16 copy of IDXI)
//   stage1: permuted prefix sum -> U (fp8 e4m3, HW cvt) + ULAST (fp32)
//           [s1a + s1c: 4-batch-per-block index-amortized]
//   k_mlp : FUSED F = relu(U@W1^T+b1)@W2^T + b2  (r17 frozen)
//   stage3: e-reduction gather over fp8 F, 4-batch index-amortized
//   final : exact fp32 last step (+ fused s3b).

#define T_STEPS 2048
#define BATCH 64
#define IN_W 256
#define SW 512
#define EPS 1e-5f
#define NCHUNK 64
#define CLEN 32
#define QSTEP 32
#define NQ 65

typedef __bf16 bf16x8 __attribute__((ext_vector_type(8)));
typedef float f32x4 __attribute__((ext_vector_type(4)));

__device__ __forceinline__ unsigned short bf16bits(float v) {
  __hip_bfloat16 h = __float2bfloat16(v);
  return *reinterpret_cast<unsigned short*>(&h);
}

__device__ __forceinline__ float bf16val(unsigned short u) {
  unsigned int x = ((unsigned int)u) << 16;
  return __uint_as_float(x);
}

// float -> OCP e4m3 via HW v_cvt_pk_fp8_f32 (RNE, saturating)
__device__ __forceinline__ unsigned char f8cvt(float v) {
  return (unsigned char)(__builtin_amdgcn_cvt_pk_fp8_f32(v, v, 0, false) & 0xff);
}
// e4m3 byte -> float via HW v_cvt_f32_fp8
__device__ __forceinline__ float f8val(unsigned char u) {
  return __builtin_amdgcn_cvt_f32_fp8((int)u, 0);
}

__device__ __forceinline__ void gload_lds16(const void* g, const void* l) {
  __builtin_amdgcn_global_load_lds(
      (const __attribute__((address_space(1))) unsigned int*)(uintptr_t)g,
      (__attribute__((address_space(3))) unsigned int*)(uintptr_t)l, 16, 0, 0);
}

// ---------------- permutation power tables (doubling) ------------------------
__global__ __launch_bounds__(512) void k_tabA(const int* __restrict__ perm,
                                              int* __restrict__ FW, int* __restrict__ IDXI) {
  __shared__ int pl[SW], il[SW];
  int j = threadIdx.x;
  pl[j] = perm[j];
  __syncthreads();
  il[pl[j]] = j;
  __syncthreads();
  int f = j, iv = j;
  FW[j] = f; IDXI[j] = iv;
  for (int t = 1; t <= QSTEP; ++t) {
    f = pl[f]; iv = il[iv];
    FW[t * SW + j] = f; IDXI[t * SW + j] = iv;
  }
}

__global__ __launch_bounds__(512) void k_tabB(const int* __restrict__ FW, const int* __restrict__ IDXI,
                                              int* __restrict__ FWQ, int* __restrict__ IDXIQ) {
  __shared__ int f32r[SW], i32r[SW];
  int j = threadIdx.x;
  f32r[j] = FW[QSTEP * SW + j];
  i32r[j] = IDXI[QSTEP * SW + j];
  __syncthreads();
  int f = j, iv = j;
  FWQ[j] = f; IDXIQ[j] = iv;
  for (int q = 1; q < NQ; ++q) {
    f = f32r[f]; iv = i32r[iv];
    FWQ[q * SW + j] = f; IDXIQ[q * SW + j] = iv;
  }
}

__global__ __launch_bounds__(512) void k_tabC(const int* __restrict__ FWQ, const int* __restrict__ IDXIQ,
                                              int* __restrict__ FW, int* __restrict__ IDXI) {
  int t = blockIdx.x;
  if (t <= QSTEP) return;
  int j = threadIdx.x;
  int q = t >> 5, r = t & 31;
  int a = FW[r * SW + j];
  FW[(size_t)t * SW + j] = FWQ[q * SW + a];
  int b = IDXI[r * SW + j];
  IDXI[(size_t)t * SW + j] = IDXIQ[q * SW + b];
}

// IDXI (int) -> IDXI16 (ushort): 2.1 MB table, fully L2-resident
__global__ __launch_bounds__(512) void k_tab16(const int* __restrict__ IDXI,
                                               unsigned short* __restrict__ IDXI16) {
  size_t i = (size_t)blockIdx.x * 512 + threadIdx.x;
  IDXI16[i] = (unsigned short)IDXI[i];
}

// ---------------- weights: W1 -> fp8 (HW cvt), W2 -> bf16 --------------------
__global__ __launch_bounds__(256) void k_wcast(const float* __restrict__ W1,
                                               const float* __restrict__ W2,
                                               unsigned char* __restrict__ W1q,
                                               __hip_bfloat16* __restrict__ W2b) {
  int i = blockIdx.x * 256 + threadIdx.x;
  if (i < SW * SW) W1q[i] = f8cvt(W1[i]);
  else W2b[i - SW * SW] = __float2bfloat16(W2[i - SW * SW]);
}

// ---------------- stage 1a: chunk sums, 4-batch index-amortized gather -------
__global__ __launch_bounds__(512) void k_s1a(const float* __restrict__ x,
                                             const unsigned short* __restrict__ IDXI16,
                                             float* __restrict__ P1) {
  __shared__ float xs[8][4][IN_W] __attribute__((aligned(16)));
  int c = blockIdx.x, b0 = blockIdx.y * 4, tid = threadIdx.x;
  float acc[4] = {0.f, 0.f, 0.f, 0.f};
  int t0 = c * CLEN;
  for (int tt = 0; tt < CLEN; tt += 8) {
#pragma unroll
    for (int s = 0; s < 4; ++s) {
      int idx = s * 512 + tid;          // 2048 float4 granules
      int row = idx >> 8;               // t-row 0..7
      int rem = idx & 255;              // 4 b x 64 granules
      int bb = rem >> 6, col = (rem & 63) * 4;
      *reinterpret_cast<f32x4*>(&xs[row][bb][col]) =
          *reinterpret_cast<const f32x4*>(
              &x[((size_t)(t0 + tt + row) * BATCH + b0 + bb) * IN_W + col]);
    }
    __syncthreads();
#pragma unroll
    for (int k = 0; k < 8; ++k) {
      int i0 = IDXI16[(size_t)(t0 + tt + k) * SW + tid];
      if (i0 < IN_W) {
#pragma unroll
        for (int bb = 0; bb < 4; ++bb) acc[bb] += xs[k][bb][i0];
      }
    }
    __syncthreads();
  }
#pragma unroll
  for (int bb = 0; bb < 4; ++bb)
    P1[((size_t)c * BATCH + b0 + bb) * SW + tid] = acc[bb];
}

// ---------------- stage 1b: chunk scan, 16-deep batched loads ----------------
__global__ __launch_bounds__(512) void k_s1b(const float* __restrict__ init,
                                             float* __restrict__ P1) {
  int b = blockIdx.x, i = threadIdx.x;
  float run = EPS * init[i];
  float v[16];
  for (int g = 0; g < NCHUNK / 16; ++g) {
#pragma unroll
    for (int k = 0; k < 16; ++k)
      v[k] = P1[((size_t)(g * 16 + k) * BATCH + b) * SW + i];
#pragma unroll
    for (int k = 0; k < 16; ++k) {
      P1[((size_t)(g * 16 + k) * BATCH + b) * SW + i] = run;
      run += v[k];
    }
  }
}

// ---------------- stage 1c: 4-batch prefix walk -> fp8 U + fp32 ULAST --------
// grid (NCHUNK, BATCH/4); xs [8][4][256] f32 (32K) + us [8][4][512] fp8 (16K)
// + ul [4][512] f32 (8K) = 56 KB. One index stream drives 4 accumulators.
__global__ __launch_bounds__(512) void k_s1c(const float* __restrict__ x,
                                             const unsigned short* __restrict__ IDXI16,
                                             const float* __restrict__ P1,
                                             unsigned char* __restrict__ U,
                                             float* __restrict__ ULAST) {
  __shared__ float xs[8][4][IN_W] __attribute__((aligned(16)));
  __shared__ unsigned char us[8][4][SW] __attribute__((aligned(16)));
  __shared__ float ul[4][SW] __attribute__((aligned(16)));
  int c = blockIdx.x, b0 = blockIdx.y * 4, tid = threadIdx.x;
  float v[4];
#pragma unroll
  for (int bb = 0; bb < 4; ++bb)
    v[bb] = P1[((size_t)c * BATCH + b0 + bb) * SW + tid];
  int t0 = c * CLEN;
  int cur = IDXI16[(size_t)t0 * SW + tid];
  for (int tt = 0; tt < CLEN; tt += 8) {
#pragma unroll
    for (int s = 0; s < 4; ++s) {
      int idx = s * 512 + tid;          // 2048 float4 granules
      int row = idx >> 8;               // t-row 0..7
      int rem = idx & 255;              // 4 b x 64 granules
      int bb = rem >> 6, col = (rem & 63) * 4;
      *reinterpret_cast<f32x4*>(&xs[row][bb][col]) =
          *reinterpret_cast<const f32x4*>(
              &x[((size_t)(t0 + tt + row) * BATCH + b0 + bb) * IN_W + col]);
    }
    __syncthreads();
#pragma unroll
    for (int k = 0; k < 8; ++k) {
      int t = t0 + tt + k;
      int nxt = IDXI16[(size_t)(t + 1) * SW + tid];
      bool in = (cur < IN_W);
#pragma unroll
      for (int bb = 0; bb < 4; ++bb) {
        if (in) v[bb] += xs[k][bb][cur];
        us[k][bb][nxt] = f8cvt(v[bb]);
      }
      if (t == T_STEPS - 1) {
#pragma unroll
        for (int bb = 0; bb < 4; ++bb) ul[bb][nxt] = v[bb];
      }
      cur = nxt;
    }
    __syncthreads();
    // dump 8 rows x 4 b x 512 fp8 = 1024 int4 granules, 2/thread
#pragma unroll
    for (int s = 0; s < 2; ++s) {
      int idx = s * 512 + tid;
      int row = idx >> 7;               // t-row 0..7
      int rem = idx & 127;              // 4 b x 32 granules
      int bb = rem >> 5, g = rem & 31;
      *reinterpret_cast<int4*>(
          U + ((size_t)(t0 + tt + row) * BATCH + b0 + bb) * SW + g * 16) =
          *reinterpret_cast<const int4*>(&us[row][bb][g * 16]);
    }
    __syncthreads();
  }
  if (c == NCHUNK - 1) {
#pragma unroll
    for (int bb = 0; bb < 4; ++bb)
      ULAST[(size_t)(b0 + bb) * SW + tid] = ul[bb][tid];
  }
}

// ---------------- FUSED MLP (round-17 verbatim, frozen) ----------------------
__global__ __launch_bounds__(512, 2) void k_mlp(const unsigned char* __restrict__ A,
                                                const unsigned char* __restrict__ W1,
                                                const __hip_bfloat16* __restrict__ W2,
                                                const float* __restrict__ b1,
                                                const float* __restrict__ b2,
                                                unsigned char* __restrict__ Fout) {
  __shared__ unsigned char smem[81920] __attribute__((aligned(16)));
  const int tid = threadIdx.x;
  const int lane = tid & 63;
  const int wv = tid >> 6;
  const int hwr = wv >> 1, hwc = wv & 1;   // phase-1 grid 4x2 (32x64 tiles)
  const int fwr = wv >> 2, fwc = wv & 3;   // phase-2 grid 2x4 (64x32 tiles)
  const size_t m0 = (size_t)blockIdx.x * 128;
  unsigned short* Hs = reinterpret_cast<unsigned short*>(smem + 49152);

  f32x4 Facc[4][4][2];                     // [n-quarter][m][n]
#pragma unroll
  for (int q = 0; q < 4; ++q)
#pragma unroll
    for (int m = 0; m < 4; ++m)
#pragma unroll
      for (int n = 0; n < 2; ++n) Facc[q][m][n] = (f32x4)0.f;

  for (int hb = 0; hb < 4; ++hb) {
    f32x4 Hacc[2][4];
#pragma unroll
    for (int m = 0; m < 2; ++m)
#pragma unroll
      for (int n = 0; n < 4; ++n) Hacc[m][n] = (f32x4)0.f;

    // ---- phase 1 (fp8): depth-3 pipeline, 2 loads/thread/stage ----
    auto stage1 = [&](int kt, int buf) {
      int row = tid >> 2, pg = tid & 3;
      int sg = pg ^ ((row >> 2) & 3);
      gload_lds16(A + (m0 + row) * 512 + kt * 64 + sg * 16,
                  (const char*)smem + buf * 8192 + tid * 16);
      gload_lds16(W1 + (size_t)(hb * 128 + row) * 512 + kt * 64 + sg * 16,
                  (const char*)smem + 24576 + buf * 8192 + tid * 16);
    };
    stage1(0, 0);
    stage1(1, 1);
#pragma unroll
    for (int kt = 0; kt < 8; ++kt) {
      if (kt < 7) asm volatile("s_waitcnt vmcnt(2)" ::: "memory");
      else        asm volatile("s_waitcnt vmcnt(0)" ::: "memory");
      __builtin_amdgcn_s_barrier();
      if (kt < 6) stage1(kt + 2, (kt + 2) % 3);
      const unsigned char* Ab = smem + (kt % 3) * 8192;
      const unsigned char* W1b_ = smem + 24576 + (kt % 3) * 8192;
#pragma unroll
      for (int kh = 0; kh < 2; ++kh) {
        long af[2], bfw[4];
        int g = kh * 4 + (lane >> 4);
#pragma unroll
        for (int m = 0; m < 2; ++m) {
          int row = hwr * 32 + m * 16 + (lane & 15);
          int off = row * 64 + ((((g >> 1) ^ ((row >> 2) & 3)) << 4) | ((g & 1) << 3));
          af[m] = *reinterpret_cast<const long*>(Ab + off);
        }
#pragma unroll
        for (int n = 0; n < 4; ++n) {
          int row = hwc * 64 + n * 16 + (lane & 15);
          int off = row * 64 + ((((g >> 1) ^ ((row >> 2) & 3)) << 4) | ((g & 1) << 3));
          bfw[n] = *reinterpret_cast<const long*>(W1b_ + off);
        }
#pragma unroll
        for (int m = 0; m < 2; ++m)
#pragma unroll
          for (int n = 0; n < 4; ++n)
            Hacc[m][n] = __builtin_amdgcn_mfma_f32_16x16x32_fp8_fp8(af[m], bfw[n], Hacc[m][n], 0, 0, 0);
      }
    }
    __syncthreads();  // all phase-1 LDS reads done

    // issue W2 round-0 (128 N-rows x 64 k bf16 = 16KB) into W2 buf 0 [0,16K)
    {
#pragma unroll
      for (int s = 0; s < 2; ++s) {
        int idx = s * 512 + tid;          // 1024 granules (128 rows x 8 of 16B)
        int row = idx >> 3, pg = idx & 7;
        int sg = pg ^ (row & 7);
        gload_lds16(W2 + (size_t)row * 512 + hb * 128 + sg * 8,
                    (const char*)smem + idx * 16);
      }
    }

    // Hacc + b1 -> relu -> bf16 Hs [128 rows][16 granules], phys = hg^(row&15)
    {
      const int rl = (lane >> 4) * 4;
      const int cl = lane & 15;
#pragma unroll
      for (int m = 0; m < 2; ++m)
#pragma unroll
        for (int n = 0; n < 4; ++n) {
          int coll = hwc * 64 + n * 16 + cl;
          float bv = b1[hb * 128 + coll];
#pragma unroll
          for (int r = 0; r < 4; ++r) {
            int rowl = hwr * 32 + m * 16 + rl + r;
            float h = Hacc[m][n][r] + bv;
            h = h > 0.f ? h : 0.f;
            int phys = (coll >> 3) ^ (rowl & 15);
            Hs[rowl * 128 + phys * 8 + (coll & 7)] = bf16bits(h);
          }
        }
    }
    __syncthreads();  // drains W2 round-0 + Hs writes

    // ---- phase 2 (bf16): 8 rounds r=(nh2=r>>1, ks=r&1), W2 tri-buffer ----
#pragma unroll
    for (int r = 0; r < 8; ++r) {
      if (r < 7) {
        int rn = r + 1;
        int nh2n = rn >> 1, ksn = rn & 1;
        int regbyte = (rn % 3) * 16384;
#pragma unroll
        for (int s = 0; s < 2; ++s) {
          int idx = s * 512 + tid;
          int row = idx >> 3, pg = idx & 7;
          int sg = pg ^ (row & 7);
          gload_lds16(W2 + (size_t)(nh2n * 128 + row) * 512 + hb * 128 + ksn * 64 + sg * 8,
                      (const char*)smem + regbyte + idx * 16);
        }
      }
      if (r > 0) {
        if (r < 7) asm volatile("s_waitcnt vmcnt(2)" ::: "memory");
        else       asm volatile("s_waitcnt vmcnt(0)" ::: "memory");
        __builtin_amdgcn_s_barrier();
      }
      const int nh2 = r >> 1, ks = r & 1;
      const unsigned short* w2b =
          reinterpret_cast<const unsigned short*>(smem + (r % 3) * 16384);
#pragma unroll
      for (int kh = 0; kh < 2; ++kh) {
        bf16x8 afH[4], bf2[2];
#pragma unroll
        for (int m = 0; m < 4; ++m) {
          int row = fwr * 64 + m * 16 + (lane & 15);
          int hg = ks * 8 + kh * 4 + (lane >> 4);
          int phys = hg ^ (row & 15);
          afH[m] = *reinterpret_cast<const bf16x8*>(&Hs[row * 128 + phys * 8]);
        }
#pragma unroll
        for (int n = 0; n < 2; ++n) {
          int row = fwc * 32 + n * 16 + (lane & 15);   // N within 128-quarter
          int lg = kh * 4 + (lane >> 4);
          int phys = lg ^ (row & 7);
          bf2[n] = *reinterpret_cast<const bf16x8*>(&w2b[row * 64 + phys * 8]);
        }
#pragma unroll
        for (int m = 0; m < 4; ++m)
#pragma unroll
          for (int n = 0; n < 2; ++n)
            Facc[nh2][m][n] = __builtin_amdgcn_mfma_f32_16x16x32_bf16(afH[m], bf2[n], Facc[nh2][m][n], 0, 0, 0);
      }
    }
    __syncthreads();  // phase-2 LDS reads done before next hb / epilogue
  }

  // ---- F epilogue (fp8): Facc + b2 -> scratch [128][256B] -> int2 stores ----
  const int rl = (lane >> 4) * 4;
  const int cl = lane & 15;
#pragma unroll
  for (int p = 0; p < 2; ++p) {      // col halves: quarters {2p, 2p+1}
#pragma unroll
    for (int qh = 0; qh < 2; ++qh) {
      int q = 2 * p + qh;
#pragma unroll
      for (int m = 0; m < 4; ++m)
#pragma unroll
        for (int n = 0; n < 2; ++n) {
          int coll = qh * 128 + fwc * 32 + n * 16 + cl;   // byte col within 256
          float bv = b2[p * 256 + coll];
#pragma unroll
          for (int r = 0; r < 4; ++r) {
            int rowl = fwr * 64 + m * 16 + rl + r;
            float v = Facc[q][m][n][r] + bv;
            int phys = (coll >> 3) ^ (rowl & 31);         // 32 8B-granules/row
            smem[rowl * 256 + phys * 8 + (coll & 7)] = f8cvt(v);
          }
        }
    }
    __syncthreads();
#pragma unroll
    for (int s = 0; s < 8; ++s) {
      int idx = s * 512 + tid;                            // 4096 = 128r x 32g
      int rowl = idx >> 5, g = idx & 31;
      int phys = g ^ (rowl & 31);
      *reinterpret_cast<int2*>(Fout + (m0 + rowl) * 512 + p * 256 + g * 8) =
          *reinterpret_cast<const int2*>(smem + rowl * 256 + phys * 8);
    }
    __syncthreads();
  }
}

// ---------------- stage 3a: 4-batch index-amortized gather (fp8 F) -----------
template <int LAST>
__global__ __launch_bounds__(512) void k_s3a(const unsigned char* __restrict__ F,
                                             const unsigned short* __restrict__ IDXI16,
                                             float* __restrict__ P3) {
  __shared__ unsigned char fs[16][4][SW] __attribute__((aligned(16)));
  int c = LAST ? (NCHUNK - 1) : blockIdx.x;
  int b0 = blockIdx.y * 4, tid = threadIdx.x;
  float acc[4] = {0.f, 0.f, 0.f, 0.f};
  int t0 = c * CLEN;
  for (int tt = 0; tt < CLEN; tt += 16) {
#pragma unroll
    for (int s = 0; s < 4; ++s) {
      int idx = s * 512 + tid;          // 2048 granules of 16B
      int row = idx >> 7;               // t-row 0..15
      int rem = idx & 127;              // 4 b x 32 granules
      int bb = rem >> 5, g = rem & 31;
      *reinterpret_cast<int4*>(&fs[row][bb][g * 16]) =
          *reinterpret_cast<const int4*>(
              &F[((size_t)(t0 + tt + row) * BATCH + b0 + bb) * SW + g * 16]);
    }
    __syncthreads();
    if (LAST) {
#pragma unroll
      for (int k = 0; k < 16; ++k) {
        int t = t0 + tt + k;
        if (t < T_STEPS - 1) {
          int i0 = IDXI16[(size_t)t * SW + tid];
#pragma unroll
          for (int bb = 0; bb < 4; ++bb) acc[bb] += f8val(fs[k][bb][i0]);
        }
      }
    } else {
#pragma unroll
      for (int k = 0; k < 16; ++k) {
        int i0 = IDXI16[(size_t)(t0 + tt + k) * SW + tid];
#pragma unroll
        for (int bb = 0; bb < 4; ++bb) acc[bb] += f8val(fs[k][bb][i0]);
      }
    }
    __syncthreads();
  }
#pragma unroll
  for (int bb = 0; bb < 4; ++bb)
    P3[((size_t)c * BATCH + b0 + bb) * SW + tid] = acc[bb];
}

// ---------------- exact fp32 final step (+ fused s3b) ------------------------
__global__ __launch_bounds__(512) void k_final(const float* __restrict__ P3,
                                               const int* __restrict__ FW,
                                               const float* __restrict__ ULAST,
                                               const float* __restrict__ W1,
                                               const float* __restrict__ b1,
                                               const float* __restrict__ W2,
                                               const float* __restrict__ b2,
                                               float* __restrict__ out) {
  __shared__ float ml[SW] __attribute__((aligned(16)));
  __shared__ float uc[SW] __attribute__((aligned(16)));
  __shared__ float hh[SW] __attribute__((aligned(16)));
  int b = blockIdx.x, j = threadIdx.x;
  float s = 0.f;
  for (int c = 0; c < NCHUNK; ++c) s += P3[((size_t)c * BATCH + b) * SW + j];
  ml[j] = s;
  __syncthreads();
  float e = ml[FW[(size_t)(T_STEPS - 1) * SW + j]];
  float u = ULAST[(size_t)b * SW + j] + EPS * e;
  uc[j] = u;
  __syncthreads();
  float pre = b1[j];
  {
    const f32x4* wr = (const f32x4*)(W1 + (size_t)j * SW);
    const f32x4* uv = (const f32x4*)uc;
    for (int k = 0; k < SW / 4; ++k) {
      f32x4 wv = wr[k], vv = uv[k];
      pre += wv[0] * vv[0] + wv[1] * vv[1] + wv[2] * vv[2] + wv[3] * vv[3];
    }
  }
  hh[j] = pre > 0.f ? pre : 0.f;
  __syncthreads();
  float d = b2[j];
  {
    const f32x4* wr = (const f32x4*)(W2 + (size_t)j * SW);
    const f32x4* hv = (const f32x4*)hh;
    for (int k = 0; k < SW / 4; ++k) {
      f32x4 wv = wr[k], vv = hv[k];
      d += wv[0] * vv[0] + wv[1] * vv[1] + wv[2] * vv[2] + wv[3] * vv[3];
    }
  }
  float sT = u + EPS * d;
  out[BATCH * 128 + (size_t)b * SW + j] = sT;                // last  [64,512]
  if (j >= SW - 128) out[b * 128 + (j - (SW - 128))] = sT;   // outputs [64,128]
}

// ---------------- host -------------------------------------------------------
extern "C" void kernel_launch(void* const* d_in, const int* in_sizes, int n_in,
                              void* d_out, int out_size, void* d_ws, size_t ws_size,
                              hipStream_t stream) {
  const float* x = (const float*)d_in[0];
  const float* init = (const float*)d_in[1];
  const float* W1 = (const float*)d_in[2];
  const float* b1 = (const float*)d_in[3];
  const float* W2 = (const float*)d_in[4];
  const float* b2 = (const float*)d_in[5];
  const int* perm = (const int*)d_in[6];
  float* out = (float*)d_out;

  char* w = (char*)d_ws;
  size_t off = 0;
  auto alloc = [&](size_t bytes) {
    size_t o = off;
    off = (off + bytes + 255) & ~(size_t)255;
    return o;
  };
  size_t oFW   = alloc((size_t)(T_STEPS + 1) * SW * 4);
  size_t oIDXI = alloc((size_t)(T_STEPS + 1) * SW * 4);
  size_t oI16  = alloc((size_t)(T_STEPS + 1) * SW * 2);
  size_t oFWQ  = alloc((size_t)NQ * SW * 4);
  size_t oIDXQ = alloc((size_t)NQ * SW * 4);
  size_t oW1q  = alloc((size_t)SW * SW);
  size_t oW2b  = alloc((size_t)SW * SW * 2);
  size_t oU    = alloc((size_t)T_STEPS * BATCH * SW);      // fp8
  size_t oF    = alloc((size_t)T_STEPS * BATCH * SW);      // fp8
  size_t oP1   = alloc((size_t)NCHUNK * BATCH * SW * 4);
  size_t oP3   = alloc((size_t)NCHUNK * BATCH * SW * 4);
  size_t oUL   = alloc((size_t)BATCH * SW * 4);
  if (off > ws_size) return;

  int* FW = (int*)(w + oFW);
  int* IDXI = (int*)(w + oIDXI);
  unsigned short* IDXI16 = (unsigned short*)(w + oI16);
  int* FWQ = (int*)(w + oFWQ);
  int* IDXIQ = (int*)(w + oIDXQ);
  unsigned char* W1q = (unsigned char*)(w + oW1q);
  __hip_bfloat16* W2b = (__hip_bfloat16*)(w + oW2b);
  unsigned char* U = (unsigned char*)(w + oU);
  unsigned char* F = (unsigned char*)(w + oF);
  float* P1 = (float*)(w + oP1);
  float* P3 = (float*)(w + oP3);
  float* ULAST = (float*)(w + oUL);

  k_tabA<<<1, 512, 0, stream>>>(perm, FW, IDXI);
  k_tabB<<<1, 512, 0, stream>>>(FW, IDXI, FWQ, IDXIQ);
  k_tabC<<<T_STEPS + 1, 512, 0, stream>>>(FWQ, IDXIQ, FW, IDXI);
  k_tab16<<<T_STEPS + 1, 512, 0, stream>>>(IDXI, IDXI16);
  k_wcast<<<(2 * SW * SW + 255) / 256, 256, 0, stream>>>(W1, W2, W1q, W2b);

  k_s1a<<<dim3(NCHUNK, BATCH / 4), 512, 0, stream>>>(x, IDXI16, P1);
  k_s1b<<<BATCH, 512, 0, stream>>>(init, P1);
  k_s1c<<<dim3(NCHUNK, BATCH / 4), 512, 0, stream>>>(x, IDXI16, P1, U, ULAST);

  k_mlp<<<(T_STEPS * BATCH) / 128, 512, 0, stream>>>(U, W1q, W2b, b1, b2, F);

  k_s3a<0><<<dim3(NCHUNK - 1, BATCH / 4), 512, 0, stream>>>(F, IDXI16, P3);
  k_s3a<1><<<dim3(1, BATCH / 4), 512, 0, stream>>>(F, IDXI16, P3);

  k_final<<<BATCH, 512, 0, stream>>>(P3, FW, ULAST, W1, b1, W2, b2, out);
}

// Round 21
// 334.024 us; speedup vs baseline: 1.0118x; 1.0118x over previous
//
#include <hip/hip_runtime.h>
#include <hip/hip_bf16.h>
#include <stdint.h>

// ResRnn via first-order expansion in eps (method err ~1e-3 << 2.62):
//   tables: pi^t / pi^-t via composition doubling (+ u16 copy of IDXI)
//   stage1: permuted prefix sum -> U (fp8 e4m3, HW cvt) + ULAST (fp32)
//           [s1a: 4-batch index-amortized; s1c: per-b (r19 best)]
//   k_mlp : FUSED F = relu(U@W1^T+b1)@W2^T + b2  (r17 frozen)
//   stage3: e-reduction gather over fp8 F, 4-batch index-amortized
//   final : exact fp32 last step (+ fused s3b).

#define T_STEPS 2048
#define BATCH 64
#define IN_W 256
#define SW 512
#define EPS 1e-5f
#define NCHUNK 64
#define CLEN 32
#define QSTEP 32
#define NQ 65

typedef __bf16 bf16x8 __attribute__((ext_vector_type(8)));
typedef float f32x4 __attribute__((ext_vector_type(4)));

__device__ __forceinline__ unsigned short bf16bits(float v) {
  __hip_bfloat16 h = __float2bfloat16(v);
  return *reinterpret_cast<unsigned short*>(&h);
}

__device__ __forceinline__ float bf16val(unsigned short u) {
  unsigned int x = ((unsigned int)u) << 16;
  return __uint_as_float(x);
}

// float -> OCP e4m3 via HW v_cvt_pk_fp8_f32 (RNE, saturating)
__device__ __forceinline__ unsigned char f8cvt(float v) {
  return (unsigned char)(__builtin_amdgcn_cvt_pk_fp8_f32(v, v, 0, false) & 0xff);
}
// e4m3 byte -> float via HW v_cvt_f32_fp8
__device__ __forceinline__ float f8val(unsigned char u) {
  return __builtin_amdgcn_cvt_f32_fp8((int)u, 0);
}

__device__ __forceinline__ void gload_lds16(const void* g, const void* l) {
  __builtin_amdgcn_global_load_lds(
      (const __attribute__((address_space(1))) unsigned int*)(uintptr_t)g,
      (__attribute__((address_space(3))) unsigned int*)(uintptr_t)l, 16, 0, 0);
}

// ---------------- permutation power tables (doubling) ------------------------
__global__ __launch_bounds__(512) void k_tabA(const int* __restrict__ perm,
                                              int* __restrict__ FW, int* __restrict__ IDXI) {
  __shared__ int pl[SW], il[SW];
  int j = threadIdx.x;
  pl[j] = perm[j];
  __syncthreads();
  il[pl[j]] = j;
  __syncthreads();
  int f = j, iv = j;
  FW[j] = f; IDXI[j] = iv;
  for (int t = 1; t <= QSTEP; ++t) {
    f = pl[f]; iv = il[iv];
    FW[t * SW + j] = f; IDXI[t * SW + j] = iv;
  }
}

__global__ __launch_bounds__(512) void k_tabB(const int* __restrict__ FW, const int* __restrict__ IDXI,
                                              int* __restrict__ FWQ, int* __restrict__ IDXIQ) {
  __shared__ int f32r[SW], i32r[SW];
  int j = threadIdx.x;
  f32r[j] = FW[QSTEP * SW + j];
  i32r[j] = IDXI[QSTEP * SW + j];
  __syncthreads();
  int f = j, iv = j;
  FWQ[j] = f; IDXIQ[j] = iv;
  for (int q = 1; q < NQ; ++q) {
    f = f32r[f]; iv = i32r[iv];
    FWQ[q * SW + j] = f; IDXIQ[q * SW + j] = iv;
  }
}

__global__ __launch_bounds__(512) void k_tabC(const int* __restrict__ FWQ, const int* __restrict__ IDXIQ,
                                              int* __restrict__ FW, int* __restrict__ IDXI) {
  int t = blockIdx.x;
  if (t <= QSTEP) return;
  int j = threadIdx.x;
  int q = t >> 5, r = t & 31;
  int a = FW[r * SW + j];
  FW[(size_t)t * SW + j] = FWQ[q * SW + a];
  int b = IDXI[r * SW + j];
  IDXI[(size_t)t * SW + j] = IDXIQ[q * SW + b];
}

// IDXI (int) -> IDXI16 (ushort): 2.1 MB table, fully L2-resident
__global__ __launch_bounds__(512) void k_tab16(const int* __restrict__ IDXI,
                                               unsigned short* __restrict__ IDXI16) {
  size_t i = (size_t)blockIdx.x * 512 + threadIdx.x;
  IDXI16[i] = (unsigned short)IDXI[i];
}

// ---------------- weights: W1 -> fp8 (HW cvt), W2 -> bf16 --------------------
__global__ __launch_bounds__(256) void k_wcast(const float* __restrict__ W1,
                                               const float* __restrict__ W2,
                                               unsigned char* __restrict__ W1q,
                                               __hip_bfloat16* __restrict__ W2b) {
  int i = blockIdx.x * 256 + threadIdx.x;
  if (i < SW * SW) W1q[i] = f8cvt(W1[i]);
  else W2b[i - SW * SW] = __float2bfloat16(W2[i - SW * SW]);
}

// ---------------- stage 1a: chunk sums, 4-batch index-amortized gather -------
__global__ __launch_bounds__(512) void k_s1a(const float* __restrict__ x,
                                             const unsigned short* __restrict__ IDXI16,
                                             float* __restrict__ P1) {
  __shared__ float xs[8][4][IN_W] __attribute__((aligned(16)));
  int c = blockIdx.x, b0 = blockIdx.y * 4, tid = threadIdx.x;
  float acc[4] = {0.f, 0.f, 0.f, 0.f};
  int t0 = c * CLEN;
  for (int tt = 0; tt < CLEN; tt += 8) {
#pragma unroll
    for (int s = 0; s < 4; ++s) {
      int idx = s * 512 + tid;          // 2048 float4 granules
      int row = idx >> 8;               // t-row 0..7
      int rem = idx & 255;              // 4 b x 64 granules
      int bb = rem >> 6, col = (rem & 63) * 4;
      *reinterpret_cast<f32x4*>(&xs[row][bb][col]) =
          *reinterpret_cast<const f32x4*>(
              &x[((size_t)(t0 + tt + row) * BATCH + b0 + bb) * IN_W + col]);
    }
    __syncthreads();
#pragma unroll
    for (int k = 0; k < 8; ++k) {
      int i0 = IDXI16[(size_t)(t0 + tt + k) * SW + tid];
      if (i0 < IN_W) {
#pragma unroll
        for (int bb = 0; bb < 4; ++bb) acc[bb] += xs[k][bb][i0];
      }
    }
    __syncthreads();
  }
#pragma unroll
  for (int bb = 0; bb < 4; ++bb)
    P1[((size_t)c * BATCH + b0 + bb) * SW + tid] = acc[bb];
}

// ---------------- stage 1b: chunk scan, 16-deep batched loads ----------------
__global__ __launch_bounds__(512) void k_s1b(const float* __restrict__ init,
                                             float* __restrict__ P1) {
  int b = blockIdx.x, i = threadIdx.x;
  float run = EPS * init[i];
  float v[16];
  for (int g = 0; g < NCHUNK / 16; ++g) {
#pragma unroll
    for (int k = 0; k < 16; ++k)
      v[k] = P1[((size_t)(g * 16 + k) * BATCH + b) * SW + i];
#pragma unroll
    for (int k = 0; k < 16; ++k) {
      P1[((size_t)(g * 16 + k) * BATCH + b) * SW + i] = run;
      run += v[k];
    }
  }
}

// ---------------- stage 1c: prefix walk -> fp8 U + fp32 ULAST (r19 best) -----
__global__ __launch_bounds__(512) void k_s1c(const float* __restrict__ x,
                                             const unsigned short* __restrict__ IDXI16,
                                             const float* __restrict__ P1,
                                             unsigned char* __restrict__ U,
                                             float* __restrict__ ULAST) {
  __shared__ float xs[16][IN_W] __attribute__((aligned(16)));
  __shared__ unsigned char us[16][SW] __attribute__((aligned(16)));
  __shared__ float ul[SW] __attribute__((aligned(16)));
  int c = blockIdx.x, b = blockIdx.y, tid = threadIdx.x;
  float v = P1[((size_t)c * BATCH + b) * SW + tid];
  int t0 = c * CLEN;
  int cur = IDXI16[(size_t)t0 * SW + tid];
  for (int tt = 0; tt < CLEN; tt += 16) {
#pragma unroll
    for (int s = 0; s < 2; ++s) {
      int idx = s * 512 + tid;
      int row = idx >> 6, col = (idx & 63) * 4;
      *reinterpret_cast<f32x4*>(&xs[row][col]) =
          *reinterpret_cast<const f32x4*>(&x[((size_t)(t0 + tt + row) * BATCH + b) * IN_W + col]);
    }
    __syncthreads();
#pragma unroll
    for (int k = 0; k < 16; ++k) {
      int t = t0 + tt + k;
      int nxt = IDXI16[(size_t)(t + 1) * SW + tid];
      if (cur < IN_W) v += xs[k][cur];
      us[k][nxt] = f8cvt(v);
      if (t == T_STEPS - 1) ul[nxt] = v;
      cur = nxt;
    }
    __syncthreads();
    {  // dump 16 rows x 512 fp8 = 512 int4, 1 per thread
      int row = tid >> 5, g = tid & 31;
      *reinterpret_cast<int4*>(U + ((size_t)(t0 + tt + row) * BATCH + b) * SW + g * 16) =
          *reinterpret_cast<const int4*>(&us[row][g * 16]);
    }
    __syncthreads();
  }
  if (c == NCHUNK - 1) ULAST[(size_t)b * SW + tid] = ul[tid];
}

// ---------------- FUSED MLP (round-17 verbatim, frozen) ----------------------
__global__ __launch_bounds__(512, 2) void k_mlp(const unsigned char* __restrict__ A,
                                                const unsigned char* __restrict__ W1,
                                                const __hip_bfloat16* __restrict__ W2,
                                                const float* __restrict__ b1,
                                                const float* __restrict__ b2,
                                                unsigned char* __restrict__ Fout) {
  __shared__ unsigned char smem[81920] __attribute__((aligned(16)));
  const int tid = threadIdx.x;
  const int lane = tid & 63;
  const int wv = tid >> 6;
  const int hwr = wv >> 1, hwc = wv & 1;   // phase-1 grid 4x2 (32x64 tiles)
  const int fwr = wv >> 2, fwc = wv & 3;   // phase-2 grid 2x4 (64x32 tiles)
  const size_t m0 = (size_t)blockIdx.x * 128;
  unsigned short* Hs = reinterpret_cast<unsigned short*>(smem + 49152);

  f32x4 Facc[4][4][2];                     // [n-quarter][m][n]
#pragma unroll
  for (int q = 0; q < 4; ++q)
#pragma unroll
    for (int m = 0; m < 4; ++m)
#pragma unroll
      for (int n = 0; n < 2; ++n) Facc[q][m][n] = (f32x4)0.f;

  for (int hb = 0; hb < 4; ++hb) {
    f32x4 Hacc[2][4];
#pragma unroll
    for (int m = 0; m < 2; ++m)
#pragma unroll
      for (int n = 0; n < 4; ++n) Hacc[m][n] = (f32x4)0.f;

    // ---- phase 1 (fp8): depth-3 pipeline, 2 loads/thread/stage ----
    auto stage1 = [&](int kt, int buf) {
      int row = tid >> 2, pg = tid & 3;
      int sg = pg ^ ((row >> 2) & 3);
      gload_lds16(A + (m0 + row) * 512 + kt * 64 + sg * 16,
                  (const char*)smem + buf * 8192 + tid * 16);
      gload_lds16(W1 + (size_t)(hb * 128 + row) * 512 + kt * 64 + sg * 16,
                  (const char*)smem + 24576 + buf * 8192 + tid * 16);
    };
    stage1(0, 0);
    stage1(1, 1);
#pragma unroll
    for (int kt = 0; kt < 8; ++kt) {
      if (kt < 7) asm volatile("s_waitcnt vmcnt(2)" ::: "memory");
      else        asm volatile("s_waitcnt vmcnt(0)" ::: "memory");
      __builtin_amdgcn_s_barrier();
      if (kt < 6) stage1(kt + 2, (kt + 2) % 3);
      const unsigned char* Ab = smem + (kt % 3) * 8192;
      const unsigned char* W1b_ = smem + 24576 + (kt % 3) * 8192;
#pragma unroll
      for (int kh = 0; kh < 2; ++kh) {
        long af[2], bfw[4];
        int g = kh * 4 + (lane >> 4);
#pragma unroll
        for (int m = 0; m < 2; ++m) {
          int row = hwr * 32 + m * 16 + (lane & 15);
          int off = row * 64 + ((((g >> 1) ^ ((row >> 2) & 3)) << 4) | ((g & 1) << 3));
          af[m] = *reinterpret_cast<const long*>(Ab + off);
        }
#pragma unroll
        for (int n = 0; n < 4; ++n) {
          int row = hwc * 64 + n * 16 + (lane & 15);
          int off = row * 64 + ((((g >> 1) ^ ((row >> 2) & 3)) << 4) | ((g & 1) << 3));
          bfw[n] = *reinterpret_cast<const long*>(W1b_ + off);
        }
#pragma unroll
        for (int m = 0; m < 2; ++m)
#pragma unroll
          for (int n = 0; n < 4; ++n)
            Hacc[m][n] = __builtin_amdgcn_mfma_f32_16x16x32_fp8_fp8(af[m], bfw[n], Hacc[m][n], 0, 0, 0);
      }
    }
    __syncthreads();  // all phase-1 LDS reads done

    // issue W2 round-0 (128 N-rows x 64 k bf16 = 16KB) into W2 buf 0 [0,16K)
    {
#pragma unroll
      for (int s = 0; s < 2; ++s) {
        int idx = s * 512 + tid;          // 1024 granules (128 rows x 8 of 16B)
        int row = idx >> 3, pg = idx & 7;
        int sg = pg ^ (row & 7);
        gload_lds16(W2 + (size_t)row * 512 + hb * 128 + sg * 8,
                    (const char*)smem + idx * 16);
      }
    }

    // Hacc + b1 -> relu -> bf16 Hs [128 rows][16 granules], phys = hg^(row&15)
    {
      const int rl = (lane >> 4) * 4;
      const int cl = lane & 15;
#pragma unroll
      for (int m = 0; m < 2; ++m)
#pragma unroll
        for (int n = 0; n < 4; ++n) {
          int coll = hwc * 64 + n * 16 + cl;
          float bv = b1[hb * 128 + coll];
#pragma unroll
          for (int r = 0; r < 4; ++r) {
            int rowl = hwr * 32 + m * 16 + rl + r;
            float h = Hacc[m][n][r] + bv;
            h = h > 0.f ? h : 0.f;
            int phys = (coll >> 3) ^ (rowl & 15);
            Hs[rowl * 128 + phys * 8 + (coll & 7)] = bf16bits(h);
          }
        }
    }
    __syncthreads();  // drains W2 round-0 + Hs writes

    // ---- phase 2 (bf16): 8 rounds r=(nh2=r>>1, ks=r&1), W2 tri-buffer ----
#pragma unroll
    for (int r = 0; r < 8; ++r) {
      if (r < 7) {
        int rn = r + 1;
        int nh2n = rn >> 1, ksn = rn & 1;
        int regbyte = (rn % 3) * 16384;
#pragma unroll
        for (int s = 0; s < 2; ++s) {
          int idx = s * 512 + tid;
          int row = idx >> 3, pg = idx & 7;
          int sg = pg ^ (row & 7);
          gload_lds16(W2 + (size_t)(nh2n * 128 + row) * 512 + hb * 128 + ksn * 64 + sg * 8,
                      (const char*)smem + regbyte + idx * 16);
        }
      }
      if (r > 0) {
        if (r < 7) asm volatile("s_waitcnt vmcnt(2)" ::: "memory");
        else       asm volatile("s_waitcnt vmcnt(0)" ::: "memory");
        __builtin_amdgcn_s_barrier();
      }
      const int nh2 = r >> 1, ks = r & 1;
      const unsigned short* w2b =
          reinterpret_cast<const unsigned short*>(smem + (r % 3) * 16384);
#pragma unroll
      for (int kh = 0; kh < 2; ++kh) {
        bf16x8 afH[4], bf2[2];
#pragma unroll
        for (int m = 0; m < 4; ++m) {
          int row = fwr * 64 + m * 16 + (lane & 15);
          int hg = ks * 8 + kh * 4 + (lane >> 4);
          int phys = hg ^ (row & 15);
          afH[m] = *reinterpret_cast<const bf16x8*>(&Hs[row * 128 + phys * 8]);
        }
#pragma unroll
        for (int n = 0; n < 2; ++n) {
          int row = fwc * 32 + n * 16 + (lane & 15);   // N within 128-quarter
          int lg = kh * 4 + (lane >> 4);
          int phys = lg ^ (row & 7);
          bf2[n] = *reinterpret_cast<const bf16x8*>(&w2b[row * 64 + phys * 8]);
        }
#pragma unroll
        for (int m = 0; m < 4; ++m)
#pragma unroll
          for (int n = 0; n < 2; ++n)
            Facc[nh2][m][n] = __builtin_amdgcn_mfma_f32_16x16x32_bf16(afH[m], bf2[n], Facc[nh2][m][n], 0, 0, 0);
      }
    }
    __syncthreads();  // phase-2 LDS reads done before next hb / epilogue
  }

  // ---- F epilogue (fp8): Facc + b2 -> scratch [128][256B] -> int2 stores ----
  const int rl = (lane >> 4) * 4;
  const int cl = lane & 15;
#pragma unroll
  for (int p = 0; p < 2; ++p) {      // col halves: quarters {2p, 2p+1}
#pragma unroll
    for (int qh = 0; qh < 2; ++qh) {
      int q = 2 * p + qh;
#pragma unroll
      for (int m = 0; m < 4; ++m)
#pragma unroll
        for (int n = 0; n < 2; ++n) {
          int coll = qh * 128 + fwc * 32 + n * 16 + cl;   // byte col within 256
          float bv = b2[p * 256 + coll];
#pragma unroll
          for (int r = 0; r < 4; ++r) {
            int rowl = fwr * 64 + m * 16 + rl + r;
            float v = Facc[q][m][n][r] + bv;
            int phys = (coll >> 3) ^ (rowl & 31);         // 32 8B-granules/row
            smem[rowl * 256 + phys * 8 + (coll & 7)] = f8cvt(v);
          }
        }
    }
    __syncthreads();
#pragma unroll
    for (int s = 0; s < 8; ++s) {
      int idx = s * 512 + tid;                            // 4096 = 128r x 32g
      int rowl = idx >> 5, g = idx & 31;
      int phys = g ^ (rowl & 31);
      *reinterpret_cast<int2*>(Fout + (m0 + rowl) * 512 + p * 256 + g * 8) =
          *reinterpret_cast<const int2*>(smem + rowl * 256 + phys * 8);
    }
    __syncthreads();
  }
}

// ---------------- stage 3a: 4-batch index-amortized gather (fp8 F) -----------
template <int LAST>
__global__ __launch_bounds__(512) void k_s3a(const unsigned char* __restrict__ F,
                                             const unsigned short* __restrict__ IDXI16,
                                             float* __restrict__ P3) {
  __shared__ unsigned char fs[16][4][SW] __attribute__((aligned(16)));
  int c = LAST ? (NCHUNK - 1) : blockIdx.x;
  int b0 = blockIdx.y * 4, tid = threadIdx.x;
  float acc[4] = {0.f, 0.f, 0.f, 0.f};
  int t0 = c * CLEN;
  for (int tt = 0; tt < CLEN; tt += 16) {
#pragma unroll
    for (int s = 0; s < 4; ++s) {
      int idx = s * 512 + tid;          // 2048 granules of 16B
      int row = idx >> 7;               // t-row 0..15
      int rem = idx & 127;              // 4 b x 32 granules
      int bb = rem >> 5, g = rem & 31;
      *reinterpret_cast<int4*>(&fs[row][bb][g * 16]) =
          *reinterpret_cast<const int4*>(
              &F[((size_t)(t0 + tt + row) * BATCH + b0 + bb) * SW + g * 16]);
    }
    __syncthreads();
    if (LAST) {
#pragma unroll
      for (int k = 0; k < 16; ++k) {
        int t = t0 + tt + k;
        if (t < T_STEPS - 1) {
          int i0 = IDXI16[(size_t)t * SW + tid];
#pragma unroll
          for (int bb = 0; bb < 4; ++bb) acc[bb] += f8val(fs[k][bb][i0]);
        }
      }
    } else {
#pragma unroll
      for (int k = 0; k < 16; ++k) {
        int i0 = IDXI16[(size_t)(t0 + tt + k) * SW + tid];
#pragma unroll
        for (int bb = 0; bb < 4; ++bb) acc[bb] += f8val(fs[k][bb][i0]);
      }
    }
    __syncthreads();
  }
#pragma unroll
  for (int bb = 0; bb < 4; ++bb)
    P3[((size_t)c * BATCH + b0 + bb) * SW + tid] = acc[bb];
}

// ---------------- exact fp32 final step (+ fused s3b) ------------------------
__global__ __launch_bounds__(512) void k_final(const float* __restrict__ P3,
                                               const int* __restrict__ FW,
                                               const float* __restrict__ ULAST,
                                               const float* __restrict__ W1,
                                               const float* __restrict__ b1,
                                               const float* __restrict__ W2,
                                               const float* __restrict__ b2,
                                               float* __restrict__ out) {
  __shared__ float ml[SW] __attribute__((aligned(16)));
  __shared__ float uc[SW] __attribute__((aligned(16)));
  __shared__ float hh[SW] __attribute__((aligned(16)));
  int b = blockIdx.x, j = threadIdx.x;
  float s = 0.f;
  for (int c = 0; c < NCHUNK; ++c) s += P3[((size_t)c * BATCH + b) * SW + j];
  ml[j] = s;
  __syncthreads();
  float e = ml[FW[(size_t)(T_STEPS - 1) * SW + j]];
  float u = ULAST[(size_t)b * SW + j] + EPS * e;
  uc[j] = u;
  __syncthreads();
  float pre = b1[j];
  {
    const f32x4* wr = (const f32x4*)(W1 + (size_t)j * SW);
    const f32x4* uv = (const f32x4*)uc;
    for (int k = 0; k < SW / 4; ++k) {
      f32x4 wv = wr[k], vv = uv[k];
      pre += wv[0] * vv[0] + wv[1] * vv[1] + wv[2] * vv[2] + wv[3] * vv[3];
    }
  }
  hh[j] = pre > 0.f ? pre : 0.f;
  __syncthreads();
  float d = b2[j];
  {
    const f32x4* wr = (const f32x4*)(W2 + (size_t)j * SW);
    const f32x4* hv = (const f32x4*)hh;
    for (int k = 0; k < SW / 4; ++k) {
      f32x4 wv = wr[k], vv = hv[k];
      d += wv[0] * vv[0] + wv[1] * vv[1] + wv[2] * vv[2] + wv[3] * vv[3];
    }
  }
  float sT = u + EPS * d;
  out[BATCH * 128 + (size_t)b * SW + j] = sT;                // last  [64,512]
  if (j >= SW - 128) out[b * 128 + (j - (SW - 128))] = sT;   // outputs [64,128]
}

// ---------------- host -------------------------------------------------------
extern "C" void kernel_launch(void* const* d_in, const int* in_sizes, int n_in,
                              void* d_out, int out_size, void* d_ws, size_t ws_size,
                              hipStream_t stream) {
  const float* x = (const float*)d_in[0];
  const float* init = (const float*)d_in[1];
  const float* W1 = (const float*)d_in[2];
  const float* b1 = (const float*)d_in[3];
  const float* W2 = (const float*)d_in[4];
  const float* b2 = (const float*)d_in[5];
  const int* perm = (const int*)d_in[6];
  float* out = (float*)d_out;

  char* w = (char*)d_ws;
  size_t off = 0;
  auto alloc = [&](size_t bytes) {
    size_t o = off;
    off = (off + bytes + 255) & ~(size_t)255;
    return o;
  };
  size_t oFW   = alloc((size_t)(T_STEPS + 1) * SW * 4);
  size_t oIDXI = alloc((size_t)(T_STEPS + 1) * SW * 4);
  size_t oI16  = alloc((size_t)(T_STEPS + 1) * SW * 2);
  size_t oFWQ  = alloc((size_t)NQ * SW * 4);
  size_t oIDXQ = alloc((size_t)NQ * SW * 4);
  size_t oW1q  = alloc((size_t)SW * SW);
  size_t oW2b  = alloc((size_t)SW * SW * 2);
  size_t oU    = alloc((size_t)T_STEPS * BATCH * SW);      // fp8
  size_t oF    = alloc((size_t)T_STEPS * BATCH * SW);      // fp8
  size_t oP1   = alloc((size_t)NCHUNK * BATCH * SW * 4);
  size_t oP3   = alloc((size_t)NCHUNK * BATCH * SW * 4);
  size_t oUL   = alloc((size_t)BATCH * SW * 4);
  if (off > ws_size) return;

  int* FW = (int*)(w + oFW);
  int* IDXI = (int*)(w + oIDXI);
  unsigned short* IDXI16 = (unsigned short*)(w + oI16);
  int* FWQ = (int*)(w + oFWQ);
  int* IDXIQ = (int*)(w + oIDXQ);
  unsigned char* W1q = (unsigned char*)(w + oW1q);
  __hip_bfloat16* W2b = (__hip_bfloat16*)(w + oW2b);
  unsigned char* U = (unsigned char*)(w + oU);
  unsigned char* F = (unsigned char*)(w + oF);
  float* P1 = (float*)(w + oP1);
  float* P3 = (float*)(w + oP3);
  float* ULAST = (float*)(w + oUL);

  k_tabA<<<1, 512, 0, stream>>>(perm, FW, IDXI);
  k_tabB<<<1, 512, 0, stream>>>(FW, IDXI, FWQ, IDXIQ);
  k_tabC<<<T_STEPS + 1, 512, 0, stream>>>(FWQ, IDXIQ, FW, IDXI);
  k_tab16<<<T_STEPS + 1, 512, 0, stream>>>(IDXI, IDXI16);
  k_wcast<<<(2 * SW * SW + 255) / 256, 256, 0, stream>>>(W1, W2, W1q, W2b);

  k_s1a<<<dim3(NCHUNK, BATCH / 4), 512, 0, stream>>>(x, IDXI16, P1);
  k_s1b<<<BATCH, 512, 0, stream>>>(init, P1);
  k_s1c<<<dim3(NCHUNK, BATCH), 512, 0, stream>>>(x, IDXI16, P1, U, ULAST);

  k_mlp<<<(T_STEPS * BATCH) / 128, 512, 0, stream>>>(U, W1q, W2b, b1, b2, F);

  k_s3a<0><<<dim3(NCHUNK - 1, BATCH / 4), 512, 0, stream>>>(F, IDXI16, P3);
  k_s3a<1><<<dim3(1, BATCH / 4), 512, 0, stream>>>(F, IDXI16, P3);

  k_final<<<BATCH, 512, 0, stream>>>(P3, FW, ULAST, W1, b1, W2, b2, out);
}